// Round 1
// baseline (319.042 us; speedup 1.0000x reference)
//
#include <hip/hip_runtime.h>
#include <math.h>

#define B_ 4
#define C_ 200
#define CH_ 100
#define W_ 300
#define WP_ 304
#define H_ 128
#define NH_ 8
#define PH_ 16
#define FF_ 512
#define L_ 2
#define MAXLEN_ 200
#define PEN_ 512
#define WVS_ 136         // LDS B-matrix row stride (bf16)
#define NTILE_ 19        // ceil(W/16)

typedef __bf16 bf16x8 __attribute__((ext_vector_type(8)));
typedef float f32x4v __attribute__((ext_vector_type(4)));

// prep grid segments (coalesced transposes, layer-merged kv)
#define SEG_PEW   512
#define SEG_KV    (SEG_PEW + B_ * W_)        // 1712
#define SEG_WR    (SEG_KV + 256)             // 1968
#define SEG_W1T   (SEG_WR + 128)             // 2096
#define PREP_BLOCKS (SEG_W1T + 128)          // 2224

// ---------------- prep: PEW | kv(both layers) | WrB copy | LDS-tiled transposes
__global__ __launch_bounds__(128) void prep_kernel(
        const float* __restrict__ Wf, const float* __restrict__ bfv,
        const float* __restrict__ words,
        const float* __restrict__ Wk, const float* __restrict__ bk,
        const float* __restrict__ Wv, const float* __restrict__ bv,
        const float* __restrict__ Wr, const float* __restrict__ W1,
        const float* __restrict__ W2,
        __bf16* __restrict__ kb, __bf16* __restrict__ PEWb, __bf16* __restrict__ vTb,
        __bf16* __restrict__ WrB, __bf16* __restrict__ W1T, __bf16* __restrict__ W2T) {
    __shared__ __align__(16) float s_row[H_];
    __shared__ float s_tile[32][33];
    int t = threadIdx.x;
    if (blockIdx.x < SEG_PEW) {
        int p = blockIdx.x;
        {
            int j = (t < 64) ? t : (t - 64);
            double f = exp(-(double)j * (log(10000.0) / 63.0));
            double a = (double)p * f;
            s_row[t] = (float)((t < 64) ? sin(a) : cos(a));
        }
        __syncthreads();
        float acc0 = 0.f, acc1 = 0.f, acc2 = 0.f, acc3 = 0.f;
        for (int j = 0; j < H_; ++j) {
            float xv = s_row[j];
            int row = j * H_ + t;
            acc0 += xv * Wf[0 * H_ * H_ + row];
            acc1 += xv * Wf[1 * H_ * H_ + row];
            acc2 += xv * Wf[2 * H_ * H_ + row];
            acc3 += xv * Wf[3 * H_ * H_ + row];
        }
        PEWb[(0 * PEN_ + p) * H_ + t] = (__bf16)(acc0 + bfv[t]);
        PEWb[(1 * PEN_ + p) * H_ + t] = (__bf16)acc1;
        PEWb[(2 * PEN_ + p) * H_ + t] = (__bf16)acc2;
        PEWb[(3 * PEN_ + p) * H_ + t] = (__bf16)acc3;
    } else if (blockIdx.x < SEG_KV) {
        int rem = blockIdx.x - SEG_PEW;
        int bb = rem / W_, w = rem % W_;
        s_row[t] = words[rem * H_ + t];
        __syncthreads();
        const float4* row4 = (const float4*)s_row;
        #pragma unroll 1
        for (int li = 0; li < L_; ++li) {
            const float* wk = Wk + li * H_ * H_;
            const float* wv = Wv + li * H_ * H_;
            float4 ak = {0,0,0,0}, av = {0,0,0,0};
            #pragma unroll 2
            for (int g = 0; g < 32; ++g) {
                float4 x = row4[g];
                int j0 = 4 * g;
                ak.x += x.x * wk[(j0 + 0) * H_ + t];
                ak.y += x.y * wk[(j0 + 1) * H_ + t];
                ak.z += x.z * wk[(j0 + 2) * H_ + t];
                ak.w += x.w * wk[(j0 + 3) * H_ + t];
                av.x += x.x * wv[(j0 + 0) * H_ + t];
                av.y += x.y * wv[(j0 + 1) * H_ + t];
                av.z += x.z * wv[(j0 + 2) * H_ + t];
                av.w += x.w * wv[(j0 + 3) * H_ + t];
            }
            kb[(size_t)(li * B_ * W_ + rem) * H_ + t] =
                (__bf16)((ak.x + ak.y) + (ak.z + ak.w) + bk[li * H_ + t]);
            size_t vrow = ((size_t)(li * B_ + bb) * H_ + t) * WP_;
            vTb[vrow + w] = (__bf16)((av.x + av.y) + (av.z + av.w) + bv[li * H_ + t]);
            if (w == 0) {
                vTb[vrow + 300] = (__bf16)0.f; vTb[vrow + 301] = (__bf16)0.f;
                vTb[vrow + 302] = (__bf16)0.f; vTb[vrow + 303] = (__bf16)0.f;
            }
        }
    } else if (blockIdx.x < SEG_WR) {
        int i = (blockIdx.x - SEG_KV) * 128 + t;
        WrB[i] = (__bf16)Wr[i];
    } else if (blockIdx.x < SEG_W1T) {
        int blk = blockIdx.x - SEG_WR;
        int l = blk >> 6;
        int rem = blk & 63;
        int jt = rem >> 4;
        int ut = rem & 15;
        int r = t >> 5, cc = t & 31;
        #pragma unroll
        for (int k = 0; k < 8; ++k) {
            int j = jt * 32 + r + 4 * k;
            s_tile[r + 4 * k][cc] = W1[(l * H_ + j) * FF_ + ut * 32 + cc];
        }
        __syncthreads();
        int jl = t & 31, ul = t >> 5;
        #pragma unroll
        for (int k = 0; k < 8; ++k) {
            int u = ut * 32 + ul + 4 * k;
            W1T[((size_t)(l * FF_ + u)) * H_ + jt * 32 + jl] = (__bf16)s_tile[jl][ul + 4 * k];
        }
    } else {
        int blk = blockIdx.x - SEG_W1T;
        int l = blk >> 6;
        int rem = blk & 63;
        int ut = rem >> 2;
        int ht = rem & 3;
        int r = t >> 5, cc = t & 31;
        #pragma unroll
        for (int k = 0; k < 8; ++k) {
            int u = ut * 32 + r + 4 * k;
            s_tile[r + 4 * k][cc] = W2[(l * FF_ + u) * H_ + ht * 32 + cc];
        }
        __syncthreads();
        int ul = t & 31, hl = t >> 5;
        #pragma unroll
        for (int k = 0; k < 8; ++k) {
            int h = ht * 32 + hl + 4 * k;
            W2T[((size_t)(l * H_ + h)) * FF_ + ut * 32 + ul] = (__bf16)s_tile[ul][hl + 4 * k];
        }
    }
}

// ---------------- mega: one block per row (b,c); fp32 in/out
// R22: un-paired rows (grid 800), no layer cache, __launch_bounds__(256,3)
// Theory: grid 400 capped residency at ~2 waves/SIMD (Occupancy 15.6%); more
// blocks + smaller reg footprint -> 3 blocks/CU resident, latency hidden.
__global__ __launch_bounds__(256, 3) void mega_kernel(
    const float* __restrict__ chars,
    const int* __restrict__ pos_s, const int* __restrict__ pos_e,
    const int* __restrict__ lex_s, const int* __restrict__ lex_e,
    const int* __restrict__ seq_len, const int* __restrict__ lex_num,
    const float* __restrict__ Wq, const float* __restrict__ bq,
    const float* __restrict__ br,
    const float* __restrict__ u_bias, const float* __restrict__ v_bias,
    const float* __restrict__ ln1_g, const float* __restrict__ ln1_b,
    const float* __restrict__ ln2_g, const float* __restrict__ ln2_b,
    const float* __restrict__ b1, const float* __restrict__ b2,
    const __bf16* __restrict__ kb, const __bf16* __restrict__ PEWb,
    const __bf16* __restrict__ vTb, const __bf16* __restrict__ WrB,
    const __bf16* __restrict__ W1T, const __bf16* __restrict__ W2T,
    float* __restrict__ out) {

    __shared__ __align__(16) float s_x[H_], s_qv[H_];
    __shared__ __align__(16) __bf16 s_wvecb[16][WVS_];
    __shared__ __align__(16) __bf16 s_qub[16][WVS_];
    __shared__ float s_bterm[NH_];
    __shared__ __align__(16) float s_sc[NH_][WP_];
    __shared__ float s_red[132];
    __shared__ __align__(16) float s_hid[FF_];
    __shared__ float s_tmp[256];
    __shared__ int s_ls[W_], s_le[W_];

    int blk = blockIdx.x;
    int b = blk / C_, c = blk % C_;
    int t = threadIdx.x;
    int lane = t & 63;
    int wid = t >> 6;
    int l15 = lane & 15, quad = lane >> 4;

    if (t < H_) s_x[t] = chars[(b * C_ + c) * H_ + t];
    for (int w = t; w < W_; w += 256) {
        s_ls[w] = lex_s[b * W_ + w];
        s_le[w] = lex_e[b * W_ + w];
    }
    for (int i = t; i < 8 * WVS_; i += 256)
        s_wvecb[8 + i / WVS_][i % WVS_] = (__bf16)0.f;
    for (int i = t; i < 16 * WVS_; i += 256)
        s_qub[i / WVS_][i % WVS_] = (__bf16)0.f;
    int ps = pos_s[b * C_ + c], pev = pos_e[b * C_ + c];
    int slen = seq_len[b];
    int cvalid = (c < slen);
    int wnum = lex_num[b];
    __syncthreads();

    #pragma unroll 1
    for (int li = 0; li < L_; ++li) {
        // ---- q projection (split-K across thread halves)
        {
            int half = t >> 7, h = t & 127;
            const float* WqL = Wq + li * H_ * H_;
            const float4* x4 = (const float4*)s_x;
            float4 a0 = {0,0,0,0};
            #pragma unroll 2
            for (int g = half * 16; g < half * 16 + 16; ++g) {
                float4 xa = x4[g];
                int j0 = 4 * g;
                a0.x += xa.x * WqL[(j0 + 0) * H_ + h];
                a0.y += xa.y * WqL[(j0 + 1) * H_ + h];
                a0.z += xa.z * WqL[(j0 + 2) * H_ + h];
                a0.w += xa.w * WqL[(j0 + 3) * H_ + h];
            }
            s_tmp[t] = (a0.x + a0.y) + (a0.z + a0.w);
        }
        __syncthreads();
        if (t < H_) {
            float acc = s_tmp[t] + s_tmp[t + 128] + bq[li * H_ + t];
            s_qub[t >> 4][t] = (__bf16)(acc + u_bias[li * H_ + t]);
            s_qv[t] = acc + v_bias[li * H_ + t];
        }
        __syncthreads();

        // ---- wvec + bterm
        if (t < H_) {
            const __bf16* WrRow = WrB + li * H_ * H_ + t * H_;
            #pragma unroll 2
            for (int n = 0; n < NH_; ++n) {
                bf16x8 w0 = *(const bf16x8*)(WrRow + n * PH_);
                bf16x8 w1 = *(const bf16x8*)(WrRow + n * PH_ + 8);
                const float4* qv4 = (const float4*)(s_qv + n * PH_);
                float4 q0 = qv4[0], q1 = qv4[1], q2 = qv4[2], q3 = qv4[3];
                float4 a4;
                a4.x = (float)w0[0] * q0.x + (float)w1[0] * q2.x;
                a4.y = (float)w0[1] * q0.y + (float)w1[1] * q2.y;
                a4.z = (float)w0[2] * q0.z + (float)w1[2] * q2.z;
                a4.w = (float)w0[3] * q0.w + (float)w1[3] * q2.w;
                a4.x += (float)w0[4] * q1.x + (float)w1[4] * q3.x;
                a4.y += (float)w0[5] * q1.y + (float)w1[5] * q3.y;
                a4.z += (float)w0[6] * q1.z + (float)w1[6] * q3.z;
                a4.w += (float)w0[7] * q1.w + (float)w1[7] * q3.w;
                s_wvecb[n][t] = (__bf16)((a4.x + a4.y) + (a4.z + a4.w));
            }
        } else if (t < H_ + NH_) {
            int n = t - H_;
            const float4* br4 = (const float4*)(br + li * H_ + n * PH_);
            float4 b0 = br4[0], b1v = br4[1], b2v = br4[2], b3v = br4[3];
            const float4* qv4 = (const float4*)(s_qv + n * PH_);
            float4 q0 = qv4[0], q1 = qv4[1], q2 = qv4[2], q3 = qv4[3];
            float4 a4;
            a4.x = b0.x * q0.x + b2v.x * q2.x;
            a4.y = b0.y * q0.y + b2v.y * q2.y;
            a4.z = b0.z * q0.z + b2v.z * q2.z;
            a4.w = b0.w * q0.w + b2v.w * q2.w;
            a4.x += b1v.x * q1.x + b3v.x * q3.x;
            a4.y += b1v.y * q1.y + b3v.y * q3.y;
            a4.z += b1v.z * q1.z + b3v.z * q3.z;
            a4.w += b1v.w * q1.w + b3v.w * q3.w;
            s_bterm[n] = (a4.x + a4.y) + (a4.z + a4.w);
        }
        __syncthreads();

        // ---- score via MFMA; rel A-fragments gathered per layer (no reg cache)
        const __bf16* kL = kb + (size_t)(li * B_ + b) * W_ * H_;
        {
            const __bf16* wrow = &s_wvecb[l15][0];
            const __bf16* qrow = &s_qub[l15][0];
            #pragma unroll
            for (int tc = 0; tc < 5; ++tc) {
                int tile = wid + 4 * tc;
                if (tile < NTILE_) {
                    int w0t = tile * 16;
                    int w = w0t + l15; if (w > W_ - 1) w = W_ - 1;
                    const __bf16* kr = kL + (size_t)w * H_;
                    f32x4v acc = {0.f,0.f,0.f,0.f};
                    int ls = s_ls[w], le = s_le[w];
                    int i0 = min(max(ps  - ls + MAXLEN_, 0), PEN_ - 1);
                    int i1 = min(max(ps  - le + MAXLEN_, 0), PEN_ - 1);
                    int i2 = min(max(pev - ls + MAXLEN_, 0), PEN_ - 1);
                    int i3 = min(max(pev - le + MAXLEN_, 0), PEN_ - 1);
                    const __bf16* r0 = PEWb + (size_t)(0 * PEN_ + i0) * H_;
                    const __bf16* r1 = PEWb + (size_t)(1 * PEN_ + i1) * H_;
                    const __bf16* r2 = PEWb + (size_t)(2 * PEN_ + i2) * H_;
                    const __bf16* r3 = PEWb + (size_t)(3 * PEN_ + i3) * H_;
                    #pragma unroll
                    for (int s = 0; s < 4; ++s) {
                        int h0 = s * 32 + quad * 8;
                        bf16x8 K = *(const bf16x8*)(kr + h0);
                        bf16x8 t0 = *(const bf16x8*)(r0 + h0);
                        bf16x8 t1 = *(const bf16x8*)(r1 + h0);
                        bf16x8 t2 = *(const bf16x8*)(r2 + h0);
                        bf16x8 t3 = *(const bf16x8*)(r3 + h0);
                        bf16x8 A;
                        #pragma unroll
                        for (int j = 0; j < 8; ++j)
                            A[j] = (__bf16)fmaxf((float)t0[j] + (float)t1[j] + (float)t2[j] + (float)t3[j], 0.f);
                        bf16x8 Bf = *(const bf16x8*)(wrow + h0);
                        acc = __builtin_amdgcn_mfma_f32_16x16x32_bf16(A, Bf, acc, 0, 0, 0);
                        bf16x8 Bq = *(const bf16x8*)(qrow + h0);
                        acc = __builtin_amdgcn_mfma_f32_16x16x32_bf16(K, Bq, acc, 0, 0, 0);
                    }
                    if (l15 < NH_) {
                        float bt = s_bterm[l15];
                        #pragma unroll
                        for (int r = 0; r < 4; ++r) {
                            int wr = w0t + quad * 4 + r;
                            if (wr < W_) s_sc[l15][wr] = acc[r] + bt;
                        }
                    }
                }
            }
        }
        __syncthreads();

        // ---- softmax per head
        {
            int n = t >> 5, ln_ = t & 31;
            if (cvalid) {
                float m = -INFINITY;
                for (int w = ln_; w < wnum; w += 32) m = fmaxf(m, s_sc[n][w]);
                #pragma unroll
                for (int off = 16; off > 0; off >>= 1) m = fmaxf(m, __shfl_xor(m, off, 32));
                float sum = 0.f;
                for (int w = ln_; w < wnum; w += 32) sum += expf(s_sc[n][w] - m);
                #pragma unroll
                for (int off = 16; off > 0; off >>= 1) sum += __shfl_xor(sum, off, 32);
                float inv = 1.f / sum;
                for (int w = ln_; w < WP_; w += 32)
                    s_sc[n][w] = (w < wnum) ? expf(s_sc[n][w] - m) * inv : 0.f;
            } else {
                for (int w = ln_; w < WP_; w += 32) s_sc[n][w] = 0.f;
            }
        }
        __syncthreads();

        // ---- ctx = att @ v (split-W across thread halves)
        {
            int h = t & 127, half = t >> 7, n = h >> 4;
            const __bf16* vrow = vTb + ((size_t)(li * B_ + b) * H_ + h) * WP_;
            const float4* att = (const float4*)(s_sc[n]);
            float4 a0 = {0,0,0,0};
            #pragma unroll 2
            for (int g = half * 19; g < half * 19 + 19; ++g) {
                bf16x8 vv = *(const bf16x8*)(vrow + 8 * g);
                float4 p0 = att[2 * g], p1 = att[2 * g + 1];
                a0.x += p0.x * (float)vv[0] + p1.x * (float)vv[4];
                a0.y += p0.y * (float)vv[1] + p1.y * (float)vv[5];
                a0.z += p0.z * (float)vv[2] + p1.z * (float)vv[6];
                a0.w += p0.w * (float)vv[3] + p1.w * (float)vv[7];
            }
            s_tmp[t] = (a0.x + a0.y) + (a0.z + a0.w);
        }
        __syncthreads();

        // ---- LN1
        if (t < 128) s_red[t] = s_tmp[t] + s_tmp[t + 128] + s_x[t];
        __syncthreads();
        if (t < 64) {
            float a = s_red[t], bb = s_red[t + 64];
            float s = a + bb, ss = a * a + bb * bb;
            #pragma unroll
            for (int off = 32; off > 0; off >>= 1) {
                s += __shfl_down(s, off);
                ss += __shfl_down(ss, off);
            }
            if (t == 0) {
                float mean = s * (1.f / 128.f);
                float var = ss * (1.f / 128.f) - mean * mean;
                s_red[128] = mean;
                s_red[129] = rsqrtf(var + 1e-5f);
            }
        }
        __syncthreads();
        if (t < H_) {
            float g1 = ln1_g[li * H_ + t], b1v = ln1_b[li * H_ + t];
            s_x[t] = (s_red[t] - s_red[128]) * s_red[129] * g1 + b1v;
        }
        __syncthreads();

        // ---- FF hidden
        {
            const __bf16* W1l = W1T + (size_t)li * FF_ * H_;
            int u0 = t * 2;
            const __bf16* ra = W1l + (size_t)u0 * H_;
            const __bf16* rb = ra + H_;
            const float4* x4 = (const float4*)s_x;
            float4 a00 = {0,0,0,0}, a01 = {0,0,0,0};
            #pragma unroll 2
            for (int g = 0; g < 16; ++g) {
                bf16x8 wa = *(const bf16x8*)(ra + 8 * g);
                bf16x8 wb = *(const bf16x8*)(rb + 8 * g);
                float4 x0 = x4[2 * g], x1 = x4[2 * g + 1];
                a00.x += x0.x * (float)wa[0] + x1.x * (float)wa[4];
                a00.y += x0.y * (float)wa[1] + x1.y * (float)wa[5];
                a00.z += x0.z * (float)wa[2] + x1.z * (float)wa[6];
                a00.w += x0.w * (float)wa[3] + x1.w * (float)wa[7];
                a01.x += x0.x * (float)wb[0] + x1.x * (float)wb[4];
                a01.y += x0.y * (float)wb[1] + x1.y * (float)wb[5];
                a01.z += x0.z * (float)wb[2] + x1.z * (float)wb[6];
                a01.w += x0.w * (float)wb[3] + x1.w * (float)wb[7];
            }
            float bb0 = b1[li * FF_ + u0], bb1 = b1[li * FF_ + u0 + 1];
            s_hid[u0]     = fmaxf((a00.x + a00.y) + (a00.z + a00.w) + bb0, 0.f);
            s_hid[u0 + 1] = fmaxf((a01.x + a01.y) + (a01.z + a01.w) + bb1, 0.f);
        }
        __syncthreads();

        // ---- FF out (split-FF across thread halves)
        {
            int half = t >> 7, h = t & 127;
            const __bf16* wrow2 = W2T + ((size_t)li * H_ + h) * FF_ + half * 256;
            const float4* h4 = (const float4*)(s_hid + half * 256);
            float4 a0 = {0,0,0,0};
            #pragma unroll 2
            for (int g = 0; g < 32; ++g) {
                bf16x8 wv = *(const bf16x8*)(wrow2 + 8 * g);
                float4 p0 = h4[2 * g], p1 = h4[2 * g + 1];
                a0.x += p0.x * (float)wv[0] + p1.x * (float)wv[4];
                a0.y += p0.y * (float)wv[1] + p1.y * (float)wv[5];
                a0.z += p0.z * (float)wv[2] + p1.z * (float)wv[6];
                a0.w += p0.w * (float)wv[3] + p1.w * (float)wv[7];
            }
            s_tmp[t] = (a0.x + a0.y) + (a0.z + a0.w);
        }
        __syncthreads();

        // ---- LN2
        if (t < 128) s_red[t] = s_tmp[t] + s_tmp[t + 128] + b2[li * H_ + t] + s_x[t];
        __syncthreads();
        if (t < 64) {
            float a = s_red[t], bb = s_red[t + 64];
            float s = a + bb, ss = a * a + bb * bb;
            #pragma unroll
            for (int off = 32; off > 0; off >>= 1) {
                s += __shfl_down(s, off);
                ss += __shfl_down(ss, off);
            }
            if (t == 0) {
                float mean = s * (1.f / 128.f);
                float var = ss * (1.f / 128.f) - mean * mean;
                s_red[128] = mean;
                s_red[129] = rsqrtf(var + 1e-5f);
            }
        }
        __syncthreads();
        if (t < H_) {
            float g2 = ln2_g[li * H_ + t], b2v = ln2_b[li * H_ + t];
            s_x[t] = (s_red[t] - s_red[128]) * s_red[129] * g2 + b2v;
        }
        __syncthreads();
    }

    if (t < H_) out[(b * C_ + c) * H_ + t] = s_x[t];
}

extern "C" void kernel_launch(void* const* d_in, const int* in_sizes, int n_in,
                              void* d_out, int out_size, void* d_ws, size_t ws_size,
                              hipStream_t stream) {
    const float* chars  = (const float*)d_in[0];
    const float* words  = (const float*)d_in[1];
    const int* pos_s   = (const int*)d_in[2];
    const int* pos_e   = (const int*)d_in[3];
    const int* lex_s   = (const int*)d_in[4];
    const int* lex_e   = (const int*)d_in[5];
    const int* seq_len = (const int*)d_in[6];
    const int* lex_num = (const int*)d_in[7];
    const float* Wf  = (const float*)d_in[8];
    const float* bfv = (const float*)d_in[9];
    const float* Wq  = (const float*)d_in[10];
    const float* bq  = (const float*)d_in[11];
    const float* Wk  = (const float*)d_in[12];
    const float* bk  = (const float*)d_in[13];
    const float* Wv  = (const float*)d_in[14];
    const float* bv  = (const float*)d_in[15];
    const float* Wr  = (const float*)d_in[16];
    const float* br  = (const float*)d_in[17];
    const float* u_bias = (const float*)d_in[18];
    const float* v_bias = (const float*)d_in[19];
    const float* ln1_g  = (const float*)d_in[20];
    const float* ln1_b  = (const float*)d_in[21];
    const float* ln2_g  = (const float*)d_in[22];
    const float* ln2_b  = (const float*)d_in[23];
    const float* W1  = (const float*)d_in[24];
    const float* b1  = (const float*)d_in[25];
    const float* W2  = (const float*)d_in[26];
    const float* b2  = (const float*)d_in[27];

    __bf16* kb   = (__bf16*)d_ws;                      // L*B*W*H  = 307200 bf16
    __bf16* PEWb = kb + (size_t)L_ * B_ * W_ * H_;     // 262144 bf16
    __bf16* vTb  = PEWb + 4 * PEN_ * H_;               // L*B*H*WP = 311296 bf16
    __bf16* WrB  = vTb + (size_t)L_ * B_ * H_ * WP_;   // 32768 bf16
    __bf16* W1T  = WrB + L_ * H_ * H_;                 // 131072 bf16
    __bf16* W2T  = W1T + L_ * H_ * FF_;                // 131072 bf16

    prep_kernel<<<dim3(PREP_BLOCKS), dim3(128), 0, stream>>>(
        Wf, bfv, words, Wk, bk, Wv, bv, Wr, W1, W2,
        kb, PEWb, vTb, WrB, W1T, W2T);

    mega_kernel<<<dim3(B_ * C_), dim3(256), 0, stream>>>(
        chars, pos_s, pos_e, lex_s, lex_e, seq_len, lex_num,
        Wq, bq, br, u_bias, v_bias,
        ln1_g, ln1_b, ln2_g, ln2_b, b1, b2,
        kb, PEWb, vTb, WrB, W1T, W2T, (float*)d_out);
}